// Round 4
// baseline (42.381 us; speedup 1.0000x reference)
//
#include <hip/hip_runtime.h>

// SurvPLE (Cox partial likelihood) loss, n = 16384.
// loss = -mean_i( (theta_i - log( sum_j exp(theta_j)*[T_j >= T_i] )) * E_i )
// T = |y|, E = (y > 0), theta = y_hat.
//
// Bucket algorithm (no sort), FUSED into one resident kernel + tiny zero kernel:
//   bucket b(T) = min(B-1, int(T*512))          (monotone in T)
//   padded bucket table: bucket b owns padded[b*C .. b*C+cnt[b])
//   risk_sum[i] = suff[b_i] + sum over bucket-b_i entries with T_j >= T_i
// Phases inside k_fused (64 blocks x 256 = 16384 threads, 1 elem/thread),
// separated by hand-rolled grid barriers (device-scope atomics + fences;
// 64 blocks << 256 CUs so all blocks are co-resident):
//   FILL -> bar -> SUFF -> bar -> MAIN -> bar -> block0 writes out.

constexpr int   B     = 4096;
constexpr int   C     = 64;       // per-bucket capacity (max occupancy ~26)
constexpr float SCALE = 512.0f;
constexpr int   GRID  = 64;       // worker blocks

__global__ __launch_bounds__(256) void k_zero(int* zbase, int nwords)
{
    const int i = blockIdx.x * 256 + threadIdx.x;
    if (i < nwords) zbase[i] = 0;
}

__device__ __forceinline__ void gbar(int* bar, int target)
{
    __syncthreads();
    if (threadIdx.x == 0) {
        __threadfence();   // release: flush this XCD's L2 (prior block writes)
        __hip_atomic_fetch_add(bar, 1, __ATOMIC_ACQ_REL, __HIP_MEMORY_SCOPE_AGENT);
        while (__hip_atomic_load(bar, __ATOMIC_ACQUIRE, __HIP_MEMORY_SCOPE_AGENT) < target) {
            __builtin_amdgcn_s_sleep(1);
        }
        __threadfence();   // acquire: invalidate stale L1/L2 before reading peers' data
    }
    __syncthreads();
}

__global__ __launch_bounds__(256) void k_fused(
    const float* __restrict__ y, const float* __restrict__ yhat,
    int* __restrict__ cnt, float* __restrict__ bw, float* __restrict__ suff,
    float2* __restrict__ padded, float* __restrict__ bsum,
    int* __restrict__ bar, float* __restrict__ out, int n)
{
    const int bk  = blockIdx.x;
    const int tid = threadIdx.x;
    const int i   = bk * 256 + tid;
    const int lane = tid & 63, wid = tid >> 6;

    __shared__ float sred[4];

    // ---- phase FILL ----
    const float yi    = y[i];
    const float theta = yhat[i];
    const float T     = fabsf(yi);
    const float w     = expf(theta);
    int b = (int)(T * SCALE);
    b = (b > B - 1) ? (B - 1) : b;

    atomicAdd(&bw[b], w);
    const int pos = atomicAdd(&cnt[b], 1);
    if (pos < C) padded[b * C + pos] = make_float2(T, w);

    gbar(bar, 1 * GRID);

    // ---- phase SUFF: suff[j] = sum_{m > j} bw[m] for this block's 64 buckets ----
    {
        // suffix offset for chunk bk: sum of bw over buckets >= (bk+1)*64
        float part = 0.0f;
        for (int j = (bk + 1) * 64 + tid; j < B; j += 256) part += bw[j];
#pragma unroll
        for (int off = 32; off > 0; off >>= 1) part += __shfl_down(part, off, 64);
        if (lane == 0) sred[wid] = part;
        __syncthreads();
        const float suffOff = sred[0] + sred[1] + sred[2] + sred[3];

        if (wid == 0) {   // wave 0: within-chunk suffix scan of 64 bucket weights
            const float v = bw[bk * 64 + lane];
            float x = v;  // inclusive suffix: x[l] = sum_{m >= l} v[m]
#pragma unroll
            for (int off = 1; off < 64; off <<= 1) {
                const float t = __shfl_down(x, off, 64);
                if (lane + off < 64) x += t;
            }
            suff[bk * 64 + lane] = suffOff + x - v;   // exclusive suffix
        }
    }

    gbar(bar, 2 * GRID);

    // ---- phase MAIN: risk sum + loss partial ----
    {
        float rs = suff[b];
        int c = cnt[b];
        c = (c > C) ? C : c;
        const float2* base = padded + (size_t)b * C;
        for (int j = 0; j < c; ++j) {
            const float2 o = base[j];
            rs += (o.x >= T) ? o.y : 0.0f;
        }

        float p = (yi > 0.0f) ? (theta - logf(rs)) : 0.0f;
#pragma unroll
        for (int off = 32; off > 0; off >>= 1) p += __shfl_down(p, off, 64);
        __syncthreads();              // sred reuse
        if (lane == 0) sred[wid] = p;
        __syncthreads();
        if (tid == 0) bsum[bk] = sred[0] + sred[1] + sred[2] + sred[3];
    }

    gbar(bar, 3 * GRID);

    // ---- block 0: deterministic final reduce + write ----
    if (bk == 0 && wid == 0) {
        float v = bsum[lane];         // GRID == 64 partials, one per lane
#pragma unroll
        for (int off = 32; off > 0; off >>= 1) v += __shfl_down(v, off, 64);
        if (lane == 0) out[0] = -v / (float)n;
    }
}

extern "C" void kernel_launch(void* const* d_in, const int* in_sizes, int n_in,
                              void* d_out, int out_size, void* d_ws, size_t ws_size,
                              hipStream_t stream) {
    const float* y    = (const float*)d_in[0];
    const float* yhat = (const float*)d_in[1];
    float* out        = (float*)d_out;
    const int n       = in_sizes[0];        // 16384

    // ws layout: [cnt B][bw B][bar 1] (zeroed) | [suff B][bsum GRID][padded B*C]
    char* p = (char*)d_ws;
    int*    cnt    = (int*)p;      p += (size_t)B * sizeof(int);
    float*  bw     = (float*)p;    p += (size_t)B * sizeof(float);
    int*    bar    = (int*)p;      p += sizeof(int);
    float*  suff   = (float*)p;    p += (size_t)B * sizeof(float);
    float*  bsum   = (float*)p;    p += (size_t)GRID * sizeof(float);
    float2* padded = (float2*)p;

    const int zwords = 2 * B + 1;
    k_zero<<<dim3((zwords + 255) / 256), dim3(256), 0, stream>>>((int*)d_ws, zwords);
    k_fused<<<dim3(GRID), dim3(256), 0, stream>>>(y, yhat, cnt, bw, suff, padded,
                                                  bsum, bar, out, n);
}

// Round 5
// 28.098 us; speedup vs baseline: 1.5083x; 1.5083x over previous
//
#include <hip/hip_runtime.h>

// SurvPLE (Cox partial likelihood) loss, n = 16384.
// loss = -mean_i( (theta_i - log( sum_j exp(theta_j)*[T_j >= T_i] )) * E_i )
// T = |y|, E = (y > 0), theta = y_hat.
//
// Bucket algorithm (no sort), 3 dispatches (dispatch boundary = cheap grid
// barrier; R4 showed spin barriers cost ~10us each, dispatch ~7us):
//   bucket b(T) = min(B-1, int(T*512))          (monotone in T)
//   padded bucket table: bucket b owns padded[b*C .. b*C+cnt[b])
//   risk_sum[i] = suffix(bw)[b_i] + sum over bucket-b_i entries with T_j >= T_i
// k_zero: zero cnt/bw/acc/done.
// k_fill: fully parallel bucketing via global atomics (64 blocks).
// k_main: per-block LDS suffix scan of the 4096 bucket weights (redundant
//         across blocks but parallel), risk sum + loss reduce, last block out.

constexpr int   B     = 4096;
constexpr int   C     = 64;       // per-bucket capacity (max occupancy ~26)
constexpr float SCALE = 512.0f;
constexpr int   BPT   = B / 256;  // buckets per thread in the scan = 16

__global__ __launch_bounds__(256) void k_zero(int* zbase, int nwords)
{
    const int i = blockIdx.x * 256 + threadIdx.x;
    if (i < nwords) zbase[i] = 0;
}

__global__ __launch_bounds__(256) void k_fill(
    const float* __restrict__ y, const float* __restrict__ yhat,
    int* __restrict__ cnt, float* __restrict__ bw, float2* __restrict__ padded)
{
    const int i = blockIdx.x * 256 + threadIdx.x;
    const float T = fabsf(y[i]);
    const float w = expf(yhat[i]);
    int b = (int)(T * SCALE);
    b = (b > B - 1) ? (B - 1) : b;
    atomicAdd(&bw[b], w);
    const int pos = atomicAdd(&cnt[b], 1);
    if (pos < C) padded[b * C + pos] = make_float2(T, w);
}

__global__ __launch_bounds__(256) void k_main(
    const float* __restrict__ y, const float* __restrict__ yhat,
    const int* __restrict__ cnt, const float* __restrict__ bw,
    const float2* __restrict__ padded, float* __restrict__ acc,
    int* __restrict__ done, float* __restrict__ out, int n)
{
    __shared__ float sbw[B];      // bucket weights -> in-place exclusive suffix
    __shared__ float sred[4];

    const int tid = threadIdx.x;
    const int i   = blockIdx.x * 256 + tid;
    const int lane = tid & 63, wid = tid >> 6;

    // stage bucket weights (L2-resident, coalesced)
    for (int j = tid; j < B; j += 256) sbw[j] = bw[j];

    // element data (overlaps with LDS load latency)
    const float yi    = y[i];
    const float theta = yhat[i];
    const float T     = fabsf(yi);
    int b = (int)(T * SCALE);
    b = (b > B - 1) ? (B - 1) : b;
    __syncthreads();

    // ---- two-level exclusive SUFFIX scan of sbw, thread owns 16 buckets ----
    const int c0 = tid * BPT;
    float s = 0.0f;
#pragma unroll
    for (int k = 0; k < BPT; ++k) s += sbw[c0 + k];

    // inclusive suffix scan of per-thread sums within wave
    float x = s;
#pragma unroll
    for (int off = 1; off < 64; off <<= 1) {
        const float t = __shfl_down(x, off, 64);
        if (lane + off < 64) x += t;
    }
    if (lane == 0) sred[wid] = x;   // wave total (suffix scan at lane 0 = sum)
    __syncthreads();
    float above = 0.0f;             // sum of wave totals for waves above this one
    for (int w2 = wid + 1; w2 < 4; ++w2) above += sred[w2];
    __syncthreads();                // sred reused later

    // exclusive suffix offset for this thread's chunk, then walk own buckets
    float run = above + (x - s);
#pragma unroll
    for (int k = BPT - 1; k >= 0; --k) {
        const float v = sbw[c0 + k];
        sbw[c0 + k] = run;          // exclusive suffix for bucket c0+k
        run += v;
    }
    __syncthreads();

    // ---- risk sum + loss ----
    float rs = sbw[b];
    int c = cnt[b];
    c = (c > C) ? C : c;
    const float2* base = padded + (size_t)b * C;
    for (int j = 0; j < c; ++j) {
        const float2 o = base[j];
        rs += (o.x >= T) ? o.y : 0.0f;
    }

    float p = (yi > 0.0f) ? (theta - logf(rs)) : 0.0f;
#pragma unroll
    for (int off = 32; off > 0; off >>= 1) p += __shfl_down(p, off, 64);
    if (lane == 0) sred[wid] = p;
    __syncthreads();
    if (tid == 0) {
        const float bs = sred[0] + sred[1] + sred[2] + sred[3];
        atomicAdd(acc, bs);
        __threadfence();
        const int old = atomicAdd(done, 1);
        if (old == (int)gridDim.x - 1) {
            const float tot = atomicAdd(acc, 0.0f);   // coherent read
            out[0] = -tot / (float)n;
        }
    }
}

extern "C" void kernel_launch(void* const* d_in, const int* in_sizes, int n_in,
                              void* d_out, int out_size, void* d_ws, size_t ws_size,
                              hipStream_t stream) {
    const float* y    = (const float*)d_in[0];
    const float* yhat = (const float*)d_in[1];
    float* out        = (float*)d_out;
    const int n       = in_sizes[0];        // 16384

    // ws layout: [cnt B][bw B][acc][done] (zeroed) | [padded B*C]
    char* p = (char*)d_ws;
    int*    cnt    = (int*)p;      p += (size_t)B * sizeof(int);
    float*  bw     = (float*)p;    p += (size_t)B * sizeof(float);
    float*  acc    = (float*)p;    p += sizeof(float);
    int*    done   = (int*)p;      p += sizeof(int);
    float2* padded = (float2*)p;

    const int zwords = 2 * B + 2;
    k_zero<<<dim3((zwords + 255) / 256), dim3(256), 0, stream>>>((int*)d_ws, zwords);
    k_fill<<<dim3(n / 256), dim3(256), 0, stream>>>(y, yhat, cnt, bw, padded);
    k_main<<<dim3(n / 256), dim3(256), 0, stream>>>(y, yhat, cnt, bw, padded,
                                                    acc, done, out, n);
}

// Round 6
// 25.831 us; speedup vs baseline: 1.6407x; 1.0878x over previous
//
#include <hip/hip_runtime.h>

// SurvPLE (Cox partial likelihood) loss, n = 16384.
// loss = -mean_i( (theta_i - log( sum_j exp(theta_j)*[T_j >= T_i] )) * E_i )
// T = |y|, E = (y > 0), theta = y_hat.
//
// Bucket algorithm, 3 dispatches (graph dispatch ~0.5us; spin barrier ~5us
// per R4 -- dispatch boundaries win). Two-level tail sums instead of the
// per-block LDS suffix scan (R5): no LDS staging, no scan, branchless.
//   fine bucket b(T) = min(B-1, int(T*512)), coarse chunk = b>>6 (64 chunks)
//   rs_i = sum_{chunk > ch_i} coarseW[chunk]            (16 float4 + 64 ops)
//        + sum_{b' in chunk ch_i, b' > b_i} fineBW[b']  (16 float4 + 64 ops)
//        + sum over padded bucket b_i entries with T_j >= T_i   (exact ties)
// k_zero: zero cnt/fineBW/coarseW/acc/done (33 KB).
// k_fill: parallel bucketing; LDS-aggregated coarse atomics.
// k_main: pure per-thread risk sum + loss reduce; acc/done finalize.

constexpr int   B     = 4096;
constexpr int   C     = 64;       // per-bucket capacity (max occupancy ~26)
constexpr float SCALE = 512.0f;

__global__ __launch_bounds__(256) void k_zero(int* zbase, int nwords)
{
    const int i = blockIdx.x * 256 + threadIdx.x;
    if (i < nwords) zbase[i] = 0;
}

__global__ __launch_bounds__(256) void k_fill(
    const float* __restrict__ y, const float* __restrict__ yhat,
    int* __restrict__ cnt, float* __restrict__ fineBW,
    float* __restrict__ coarseW, float2* __restrict__ padded)
{
    __shared__ float scw[64];
    const int tid = threadIdx.x;
    const int i   = blockIdx.x * 256 + tid;

    if (tid < 64) scw[tid] = 0.0f;
    __syncthreads();

    const float T = fabsf(y[i]);
    const float w = expf(yhat[i]);
    int b = (int)(T * SCALE);
    b = (b > B - 1) ? (B - 1) : b;

    atomicAdd(&fineBW[b], w);
    atomicAdd(&scw[b >> 6], w);
    const int pos = atomicAdd(&cnt[b], 1);
    if (pos < C) padded[b * C + pos] = make_float2(T, w);

    __syncthreads();
    if (tid < 64 && scw[tid] != 0.0f) atomicAdd(&coarseW[tid], scw[tid]);
}

__global__ __launch_bounds__(256) void k_main(
    const float* __restrict__ y, const float* __restrict__ yhat,
    const int* __restrict__ cnt, const float* __restrict__ fineBW,
    const float* __restrict__ coarseW, const float2* __restrict__ padded,
    float* __restrict__ acc, int* __restrict__ done,
    float* __restrict__ out, int n)
{
    const int tid = threadIdx.x;
    const int i   = blockIdx.x * 256 + tid;
    const int lane = tid & 63, wid = tid >> 6;

    const float yi    = y[i];
    const float theta = yhat[i];
    const float T     = fabsf(yi);
    int b = (int)(T * SCALE);
    b = (b > B - 1) ? (B - 1) : b;
    const int ch = b >> 6;
    const int bl = b & 63;

    int c = cnt[b];                       // issue early (L2 latency)
    c = (c > C) ? C : c;

    float rs = 0.0f;

    // coarse tail: chunks strictly above ch (branchless, broadcast loads)
    const float4* cw4 = (const float4*)coarseW;
#pragma unroll
    for (int q = 0; q < 16; ++q) {
        const float4 v = cw4[q];
        const int j0 = q * 4;
        rs += ((j0 + 0) > ch ? v.x : 0.0f);
        rs += ((j0 + 1) > ch ? v.y : 0.0f);
        rs += ((j0 + 2) > ch ? v.z : 0.0f);
        rs += ((j0 + 3) > ch ? v.w : 0.0f);
    }

    // fine tail: buckets strictly above b within own chunk
    const float4* fw4 = (const float4*)(fineBW + (ch << 6));
#pragma unroll
    for (int q = 0; q < 16; ++q) {
        const float4 v = fw4[q];
        const int j0 = q * 4;
        rs += ((j0 + 0) > bl ? v.x : 0.0f);
        rs += ((j0 + 1) > bl ? v.y : 0.0f);
        rs += ((j0 + 2) > bl ? v.z : 0.0f);
        rs += ((j0 + 3) > bl ? v.w : 0.0f);
    }

    // exact in-bucket ties (includes self), 2 entries per float4 load
    const float4* base4 = (const float4*)(padded + (size_t)b * C);
    const int pairs = c >> 1;
    for (int q = 0; q < pairs; ++q) {
        const float4 e = base4[q];
        rs += (e.x >= T ? e.y : 0.0f);
        rs += (e.z >= T ? e.w : 0.0f);
    }
    if (c & 1) {
        const float2 o = padded[(size_t)b * C + (c - 1)];
        rs += (o.x >= T ? o.y : 0.0f);
    }

    float p = (yi > 0.0f) ? (theta - logf(rs)) : 0.0f;

#pragma unroll
    for (int off = 32; off > 0; off >>= 1) p += __shfl_down(p, off, 64);

    __shared__ float sred[4];
    if (lane == 0) sred[wid] = p;
    __syncthreads();
    if (tid == 0) {
        const float bs = sred[0] + sred[1] + sred[2] + sred[3];
        atomicAdd(acc, bs);
        __threadfence();
        const int old = atomicAdd(done, 1);
        if (old == (int)gridDim.x - 1) {
            const float tot = atomicAdd(acc, 0.0f);   // coherent read
            out[0] = -tot / (float)n;
        }
    }
}

extern "C" void kernel_launch(void* const* d_in, const int* in_sizes, int n_in,
                              void* d_out, int out_size, void* d_ws, size_t ws_size,
                              hipStream_t stream) {
    const float* y    = (const float*)d_in[0];
    const float* yhat = (const float*)d_in[1];
    float* out        = (float*)d_out;
    const int n       = in_sizes[0];        // 16384

    // ws layout: [padded B*C float2 (2MB, 16B-aligned)] |
    //            [cnt B][fineBW B][coarseW 64][acc][done]  <- zeroed each call
    char* p = (char*)d_ws;
    float2* padded  = (float2*)p;  p += (size_t)B * C * sizeof(float2);
    int*    zbase   = (int*)p;
    int*    cnt     = (int*)p;     p += (size_t)B * sizeof(int);
    float*  fineBW  = (float*)p;   p += (size_t)B * sizeof(float);
    float*  coarseW = (float*)p;   p += 64 * sizeof(float);
    float*  acc     = (float*)p;   p += sizeof(float);
    int*    done    = (int*)p;

    const int zwords = B + B + 64 + 2;
    k_zero<<<dim3((zwords + 255) / 256), dim3(256), 0, stream>>>(zbase, zwords);
    k_fill<<<dim3(n / 256), dim3(256), 0, stream>>>(y, yhat, cnt, fineBW,
                                                    coarseW, padded);
    k_main<<<dim3(n / 256), dim3(256), 0, stream>>>(y, yhat, cnt, fineBW, coarseW,
                                                    padded, acc, done, out, n);
}